// Round 6
// baseline (398.587 us; speedup 1.0000x reference)
//
#include <hip/hip_runtime.h>

typedef float fvec4 __attribute__((ext_vector_type(4)));
typedef float fvec2 __attribute__((ext_vector_type(2)));
typedef float f32x4 __attribute__((ext_vector_type(4)));
typedef short bf16x8 __attribute__((ext_vector_type(8)));

#define D   128   // D_IN == D_OUT
#define CAP 64    // adjacency slots per vertex (deg ~ Poisson(12); P(>64)~1e-30)

static __device__ __forceinline__ unsigned bcu(float f) {
    return __builtin_bit_cast(unsigned, f);
}
// pack two fp32 (round-half-up to bf16) into one u32 (lo elem in low half)
static __device__ __forceinline__ unsigned pack_bf2(float f0, float f1) {
    unsigned a0 = bcu(f0) + 0x8000u;
    unsigned a1 = bcu(f1) + 0x8000u;
    return __builtin_amdgcn_perm(a1, a0, 0x07060302u);
}
// full-precision RNE for the (tiny) weight prep
static __device__ __forceinline__ unsigned short f2bf_rne(float f) {
    unsigned u = bcu(f);
    u += 0x7FFFu + ((u >> 16) & 1u);
    return (unsigned short)(u >> 16);
}

// ---------------------------------------------------------------------------
// P0 (fused): (a) build swizzled transposed weight triple Wsw (bf16) with
// COALESCED W reads; (b) zero counts[].
// Source (p,k,col) -> dest row=col, c = ((k>>3) ^ (col&15))*8 + (k&7).
// The swizzle makes the GEMM's ds_read_b128 pattern conflict-free while the
// global->LDS staging stays a pure linear lane-order copy.
// ---------------------------------------------------------------------------
__global__ __launch_bounds__(256) void prep_zero(
    const float* __restrict__ Wf, const float* __restrict__ Wb,
    const float* __restrict__ Ws, unsigned short* __restrict__ Wsw,
    int* __restrict__ counts, int N)
{
    const int t = blockIdx.x * 256 + threadIdx.x;
    const int totalW = 3 * 128 * 128;
    if (t < totalW) {
        int p   = t >> 14;
        int e   = t & 16383;
        int k   = e >> 7;
        int col = e & 127;               // coalesced read along col
        const float* W = (p == 0) ? Wf : (p == 1) ? Wb : Ws;
        float val = W[k * D + col];
        int c = (((k >> 3) ^ (col & 15)) << 3) | (k & 7);
        Wsw[p * 16384 + col * 128 + c] = f2bf_rne(val);
    } else {
        int z = t - totalW;
        if (z < N) counts[z] = 0;
    }
}

// ---------------------------------------------------------------------------
// K1 (fused): MFMA GEMM (all 3 matrices per block) + adjacency fill,
// interleaved 1 GEMM : 3 fill via (bid & 3) so the fill atomics hide under
// GEMM memory time.
// GEMM block: 64 rows x 384 cols; 4 waves; wave tile 16 rows x 128 cols per
// pass; 32 acc/thread reused across the 3 passes.
//   - x fragments AND drop_u prefetched into registers up front (drop_u
//     compressed to a 32-bit keep-mask after the first barrier).
//   - W for the current pass staged into 32 KB LDS via global_load_lds w=16;
//     next pass's staging issued right after the done-reading barrier.
// Fill: 2 threads/edge; atomic cursor on counts[] + direct bucket write:
// adj[v*CAP+pos] = source row in combined Y (Yf rows [0,N), Yb rows [N,2N)).
// ---------------------------------------------------------------------------
__global__ __launch_bounds__(256, 4) void mm3_fill(
    const float* __restrict__ x,
    const unsigned short* __restrict__ Wsw,
    const float* __restrict__ drop_u,
    unsigned short* __restrict__ Y,    // bf16 [2N][128]
    float* __restrict__ out,
    const int* __restrict__ send, const int* __restrict__ recv,
    int* __restrict__ counts, int* __restrict__ adj,
    int N, int E, int Nb)
{
    __shared__ unsigned short ldsW[128 * 128];   // 32 KB, one pass of W

    const int bid = blockIdx.x;

    if (bid & 3) {
        // ---- adjacency fill portion (3 of every 4 blocks) ----
        int fi = (bid >> 2) * 3 + (bid & 3) - 1;
        int t = fi * 256 + threadIdx.x;
        int e = t >> 1;
        if (e < E) {
            int v, src;
            if (t & 1) { v = recv[e]; src = send[e]; }      // fwd: Yf[send]->recv
            else       { v = send[e]; src = N + recv[e]; }  // bwd: Yb[recv]->send
            int pos = atomicAdd(counts + v, 1);
            if (pos < CAP) adj[v * CAP + pos] = src;
        }
        return;
    }

    // ---- GEMM portion ----
    const int gb   = bid >> 2;          // 0..Nb-1
    const int wave = threadIdx.x >> 6;
    const int lane = threadIdx.x & 63;
    const int quad = lane >> 4;
    const int m16  = lane & 15;

    const int row  = gb * 64 + wave * 16 + m16;
    const int rowc = (row < N) ? row : N - 1;     // clamp loads; stores guarded
    const float* xp = x + (size_t)rowc * D;

    // stage W[pass] into LDS: 8 rounds x 256 lanes x 16 B = 32 KB linear copy
    auto stage = [&](int p) {
        const char* src = (const char*)(Wsw + (size_t)p * 16384);
#pragma unroll
        for (int r = 0; r < 8; ++r) {
            const int unit = r * 256 + wave * 64;   // wave-uniform LDS base
            __builtin_amdgcn_global_load_lds(
                (const __attribute__((address_space(1))) unsigned*)
                    (src + (size_t)(unit + lane) * 16),
                (__attribute__((address_space(3))) unsigned*)
                    ((char*)ldsW + (size_t)unit * 16),
                16, 0, 0);
        }
    };

    // issue x loads + drop_u loads (HBM) then pass-0 staging (L2):
    // everything in flight before the first barrier drain
    fvec4 xlo[4], xhi[4];
#pragma unroll
    for (int kc = 0; kc < 4; ++kc) {
        xlo[kc] = *(const fvec4*)(xp + kc * 32 + quad * 8);
        xhi[kc] = *(const fvec4*)(xp + kc * 32 + quad * 8 + 4);
    }
    fvec4 ur[8];
#pragma unroll
    for (int ct = 0; ct < 8; ++ct)
        ur[ct] = *(const fvec4*)(drop_u + (size_t)rowc * D + ct * 16 + quad * 4);
    stage(0);

    // pack x to bf16 fragments
    bf16x8 xf[4];
#pragma unroll
    for (int kc = 0; kc < 4; ++kc) {
        uint4 xi;
        xi.x = pack_bf2(xlo[kc][0], xlo[kc][1]);
        xi.y = pack_bf2(xlo[kc][2], xlo[kc][3]);
        xi.z = pack_bf2(xhi[kc][0], xhi[kc][1]);
        xi.w = pack_bf2(xhi[kc][2], xhi[kc][3]);
        xf[kc] = __builtin_bit_cast(bf16x8, xi);
    }

    __syncthreads();   // staging + x + drop_u loads complete

    // compress dropout to 32-bit keep-mask (frees 32 VGPRs)
    unsigned dmask = 0;
#pragma unroll
    for (int ct = 0; ct < 8; ++ct)
#pragma unroll
        for (int c = 0; c < 4; ++c)
            dmask |= (ur[ct][c] < 0.8f) ? (1u << (ct * 4 + c)) : 0u;

#pragma unroll
    for (int pass = 0; pass < 3; ++pass) {
        f32x4 C[8];
#pragma unroll
        for (int ct = 0; ct < 8; ++ct) C[ct] = (f32x4){0.f, 0.f, 0.f, 0.f};

#pragma unroll
        for (int kc = 0; kc < 4; ++kc) {
#pragma unroll
            for (int ct = 0; ct < 8; ++ct) {
                // swizzled LDS read: row = ct*16+m16, unit = (kc*4+quad)^m16
                const unsigned short* wp =
                    ldsW + (size_t)(ct * 16 + m16) * 128 +
                    (((kc * 4 + quad) ^ m16) * 8);
                bf16x8 wf = *(const bf16x8*)wp;
                C[ct] = __builtin_amdgcn_mfma_f32_16x16x32_bf16(
                    wf, xf[kc], C[ct], 0, 0, 0);
            }
        }

        if (pass < 2) {
            __syncthreads();     // done reading ldsW for this pass
            stage(pass + 1);     // overlap next staging with epilogue
        }

        // epilogue (no loads left on the critical path)
        if (row < N) {
            if (pass == 2) {
#pragma unroll
                for (int ct = 0; ct < 8; ++ct) {
                    fvec4 r;
#pragma unroll
                    for (int c = 0; c < 4; ++c)
                        r[c] = C[ct][c] *
                               (((dmask >> (ct * 4 + c)) & 1u) ? 1.25f : 0.0f);
                    *(fvec4*)(out + (size_t)row * D + ct * 16 + quad * 4) = r;
                }
            } else {
                unsigned short* Yp = Y + (size_t)pass * N * D;
#pragma unroll
                for (int ct = 0; ct < 8; ++ct) {
                    uint2 pk;
                    pk.x = pack_bf2(C[ct][0], C[ct][1]);
                    pk.y = pack_bf2(C[ct][2], C[ct][3]);
                    *(uint2*)(Yp + (size_t)row * D + ct * 16 + quad * 4) = pk;
                }
            }
        }

        if (pass < 2) __syncthreads();   // next pass's W staged
    }
}

// ---------------------------------------------------------------------------
// K2: gather-sum + self-loop + ReLU.  One wave per output row.
// Adjacency read as broadcast int4 (4 entries/wave-step), software-pipelined
// one int4 ahead; Y-row loads 2-deep (grp = lane>>4 picks the entry, l16 =
// lane&15 reads 16 B of that row). shfl_xor(16/32) cross-grp reduce; fully
// coalesced 8 B/lane RMW epilogue.
// ---------------------------------------------------------------------------
static __device__ __forceinline__ float bflo(unsigned u) {
    return __builtin_bit_cast(float, u << 16);
}
static __device__ __forceinline__ float bfhi(unsigned u) {
    return __builtin_bit_cast(float, u & 0xFFFF0000u);
}
static __device__ __forceinline__ int pick(int4 a, int grp) {
    return (grp == 0) ? a.x : (grp == 1) ? a.y : (grp == 2) ? a.z : a.w;
}

__global__ __launch_bounds__(256) void gather_kernel(
    const unsigned short* __restrict__ Y, const int* __restrict__ counts,
    const int* __restrict__ adj, float* __restrict__ out, int N)
{
    const int wave = threadIdx.x >> 6;
    const int v = blockIdx.x * 4 + wave;
    if (v >= N) return;
    const int lane = threadIdx.x & 63;
    const int grp = lane >> 4;
    const int l16 = lane & 15;

    int deg = counts[v];
    if (deg > CAP) deg = CAP;
    const int* ap = adj + (size_t)v * CAP;

    float acc[8];
#pragma unroll
    for (int i = 0; i < 8; ++i) acc[i] = 0.0f;

    int4 av = *(const int4*)ap;   // entries 0..3 (unused if deg==0)
    int j = 0;

    // 2-deep: 8 entries, 2 concurrent dwordx4 rounds per iteration
    for (; j + 8 < deg; j += 8) {
        int4 nv  = *(const int4*)(ap + j + 4);
        int4 nv2 = *(const int4*)(ap + j + 8);
        uint4 u0 = *(const uint4*)(Y + (size_t)pick(av, grp) * D + l16 * 8);
        uint4 u1 = *(const uint4*)(Y + (size_t)pick(nv, grp) * D + l16 * 8);
        acc[0] += bflo(u0.x); acc[1] += bfhi(u0.x);
        acc[2] += bflo(u0.y); acc[3] += bfhi(u0.y);
        acc[4] += bflo(u0.z); acc[5] += bfhi(u0.z);
        acc[6] += bflo(u0.w); acc[7] += bfhi(u0.w);
        acc[0] += bflo(u1.x); acc[1] += bfhi(u1.x);
        acc[2] += bflo(u1.y); acc[3] += bfhi(u1.y);
        acc[4] += bflo(u1.z); acc[5] += bfhi(u1.z);
        acc[6] += bflo(u1.w); acc[7] += bfhi(u1.w);
        av = nv2;
    }
    // 1-deep: 4 entries per iteration
    for (; j + 4 < deg; j += 4) {
        int4 nv = *(const int4*)(ap + j + 4);
        uint4 u0 = *(const uint4*)(Y + (size_t)pick(av, grp) * D + l16 * 8);
        acc[0] += bflo(u0.x); acc[1] += bfhi(u0.x);
        acc[2] += bflo(u0.y); acc[3] += bfhi(u0.y);
        acc[4] += bflo(u0.z); acc[5] += bfhi(u0.z);
        acc[6] += bflo(u0.w); acc[7] += bfhi(u0.w);
        av = nv;
    }
    // tail: entries j..deg-1 (av already holds them)
    if (j + grp < deg) {
        uint4 u0 = *(const uint4*)(Y + (size_t)pick(av, grp) * D + l16 * 8);
        acc[0] += bflo(u0.x); acc[1] += bfhi(u0.x);
        acc[2] += bflo(u0.y); acc[3] += bfhi(u0.y);
        acc[4] += bflo(u0.z); acc[5] += bfhi(u0.z);
        acc[6] += bflo(u0.w); acc[7] += bfhi(u0.w);
    }

#pragma unroll
    for (int i = 0; i < 8; ++i) {
        acc[i] += __shfl_xor(acc[i], 16, 64);
        acc[i] += __shfl_xor(acc[i], 32, 64);
    }

    float e0, e1;
    if (grp == 0)      { e0 = acc[0]; e1 = acc[1]; }
    else if (grp == 1) { e0 = acc[2]; e1 = acc[3]; }
    else if (grp == 2) { e0 = acc[4]; e1 = acc[5]; }
    else               { e0 = acc[6]; e1 = acc[7]; }

    float* po = out + (size_t)v * D + l16 * 8 + grp * 2;
    fvec2 o = *(fvec2*)po;
    o.x = fmaxf(o.x + e0, 0.0f);
    o.y = fmaxf(o.y + e1, 0.0f);
    *(fvec2*)po = o;
}

extern "C" void kernel_launch(void* const* d_in, const int* in_sizes, int n_in,
                              void* d_out, int out_size, void* d_ws, size_t ws_size,
                              hipStream_t stream)
{
    const float* x      = (const float*)d_in[0];
    const float* W_f    = (const float*)d_in[1];
    const float* W_b    = (const float*)d_in[2];
    const float* W_s    = (const float*)d_in[3];
    const float* drop_u = (const float*)d_in[4];
    const int*   send   = (const int*)d_in[5];
    const int*   recv   = (const int*)d_in[6];

    const int N = in_sizes[0] / D;   // 100000
    const int E = in_sizes[5];       // 600000

    float* out = (float*)d_out;

    // workspace layout (16B-aligned chunks):
    //   Wsw    : 3*128*128 bf16 (96 KB, pre-swizzled)
    //   Y      : 2*N*128 bf16 (51.2 MB)
    //   counts : N ints (0.4 MB)
    //   adj    : N*CAP ints (25.6 MB)
    unsigned short* Wsw = (unsigned short*)d_ws;
    unsigned short* Y   = Wsw + (size_t)3 * 128 * 128;
    int* counts = (int*)(Y + (size_t)2 * N * D);
    int* adj    = counts + ((N + 3) & ~3);

    const int Nb = (N + 63) / 64;    // 1563 GEMM blocks

    // P0: swizzled W prep + counts zeroing (one small dispatch)
    prep_zero<<<(3 * 128 * 128 + N + 255) / 256, 256, 0, stream>>>(
        W_f, W_b, W_s, Wsw, counts, N);

    // K1: fused MFMA GEMM + adjacency fill, interleaved 1:3
    // fill capacity: 3*Nb blocks * 256 thr = 1,200,384 >= 2E = 1,200,000
    mm3_fill<<<4 * Nb, 256, 0, stream>>>(
        x, Wsw, drop_u, Y, out, send, recv, counts, adj, N, E, Nb);

    // K2: gather + self-loop + ReLU
    gather_kernel<<<(N + 3) / 4, 256, 0, stream>>>(Y, counts, adj, out, N);
}

// Round 7
// 330.082 us; speedup vs baseline: 1.2075x; 1.2075x over previous
//
#include <hip/hip_runtime.h>

typedef float fvec4 __attribute__((ext_vector_type(4)));
typedef float fvec2 __attribute__((ext_vector_type(2)));
typedef float f32x4 __attribute__((ext_vector_type(4)));
typedef short bf16x8 __attribute__((ext_vector_type(8)));

#define D   128   // D_IN == D_OUT
#define CAP 64    // adjacency slots per vertex (deg ~ Poisson(12); P(>64)~1e-30)

static __device__ __forceinline__ unsigned bcu(float f) {
    return __builtin_bit_cast(unsigned, f);
}
// pack two fp32 (round-half-up to bf16) into one u32 (lo elem in low half)
static __device__ __forceinline__ unsigned pack_bf2(float f0, float f1) {
    unsigned a0 = bcu(f0) + 0x8000u;
    unsigned a1 = bcu(f1) + 0x8000u;
    return __builtin_amdgcn_perm(a1, a0, 0x07060302u);
}
// full-precision RNE for the (tiny) weight prep
static __device__ __forceinline__ unsigned short f2bf_rne(float f) {
    unsigned u = bcu(f);
    u += 0x7FFFu + ((u >> 16) & 1u);
    return (unsigned short)(u >> 16);
}

// ---------------------------------------------------------------------------
// P0 (fused): (a) build swizzled transposed weight triple Wsw (bf16) with
// coalesced W reads; (b) zero counts[].
// Source (p,k,col) -> dest row=col, c = ((k>>3) ^ (col&15))*8 + (k&7).
// Swizzle makes the GEMM's ds_read_b128 pattern conflict-free while the
// global->LDS staging stays a pure linear lane-order copy.
// ---------------------------------------------------------------------------
__global__ __launch_bounds__(256) void prep_zero(
    const float* __restrict__ Wf, const float* __restrict__ Wb,
    const float* __restrict__ Ws, unsigned short* __restrict__ Wsw,
    int* __restrict__ counts, int N)
{
    const int t = blockIdx.x * 256 + threadIdx.x;
    const int totalW = 3 * 128 * 128;
    if (t < totalW) {
        int p   = t >> 14;
        int e   = t & 16383;
        int k   = e >> 7;
        int col = e & 127;               // coalesced read along col
        const float* W = (p == 0) ? Wf : (p == 1) ? Wb : Ws;
        float val = W[k * D + col];
        int c = (((k >> 3) ^ (col & 15)) << 3) | (k & 7);
        Wsw[p * 16384 + col * 128 + c] = f2bf_rne(val);
    } else {
        int z = t - totalW;
        if (z < N) counts[z] = 0;
    }
}

// ---------------------------------------------------------------------------
// K1 (fused): MFMA GEMM (all 3 matrices per block) + adjacency fill TAIL.
// (Round-6 interleave regressed 2.5x: fill atomics contend with the GEMM's
//  latency-critical loads. Tail placement is the measured-best layout.)
// GEMM blocks [0, Nb): 64 rows x 384 cols; 4 waves; wave tile 16 rows x 128
// cols per pass; 32 acc/thread reused across the 3 passes.
//   - x fragments AND drop_u prefetched into registers up front (drop_u
//     compressed to a 32-bit keep-mask after the first barrier).
//   - W for the current pass staged into 32 KB LDS via global_load_lds w=16;
//     next pass's staging issued right after the done-reading barrier.
// Fill blocks [Nb, ...): 2 threads/edge; atomic cursor on counts[] + direct
// bucket write: adj[v*CAP+pos] = source row in combined Y
// (Yf rows [0,N) = forward from send, Yb rows [N,2N) = backward from recv).
// ---------------------------------------------------------------------------
__global__ __launch_bounds__(256, 4) void mm3_fill(
    const float* __restrict__ x,
    const unsigned short* __restrict__ Wsw,
    const float* __restrict__ drop_u,
    unsigned short* __restrict__ Y,    // bf16 [2N][128]
    float* __restrict__ out,
    const int* __restrict__ send, const int* __restrict__ recv,
    int* __restrict__ counts, int* __restrict__ adj,
    int N, int E, int Nb)
{
    __shared__ unsigned short ldsW[128 * 128];   // 32 KB, one pass of W

    const int bid = blockIdx.x;

    if (bid >= Nb) {
        // ---- adjacency fill portion (tail blocks) ----
        int t = (bid - Nb) * 256 + threadIdx.x;
        int e = t >> 1;
        if (e < E) {
            int v, src;
            if (t & 1) { v = recv[e]; src = send[e]; }      // fwd: Yf[send]->recv
            else       { v = send[e]; src = N + recv[e]; }  // bwd: Yb[recv]->send
            int pos = atomicAdd(counts + v, 1);
            if (pos < CAP) adj[v * CAP + pos] = src;
        }
        return;
    }

    // ---- GEMM portion ----
    const int wave = threadIdx.x >> 6;
    const int lane = threadIdx.x & 63;
    const int quad = lane >> 4;
    const int m16  = lane & 15;

    const int row  = bid * 64 + wave * 16 + m16;
    const int rowc = (row < N) ? row : N - 1;     // clamp loads; stores guarded
    const float* xp = x + (size_t)rowc * D;

    // stage W[pass] into LDS: 8 rounds x 256 lanes x 16 B = 32 KB linear copy
    auto stage = [&](int p) {
        const char* src = (const char*)(Wsw + (size_t)p * 16384);
#pragma unroll
        for (int r = 0; r < 8; ++r) {
            const int unit = r * 256 + wave * 64;   // wave-uniform LDS base
            __builtin_amdgcn_global_load_lds(
                (const __attribute__((address_space(1))) unsigned*)
                    (src + (size_t)(unit + lane) * 16),
                (__attribute__((address_space(3))) unsigned*)
                    ((char*)ldsW + (size_t)unit * 16),
                16, 0, 0);
        }
    };

    // issue x loads + drop_u loads (HBM) then pass-0 staging (L2):
    // everything in flight before the first barrier drain
    fvec4 xlo[4], xhi[4];
#pragma unroll
    for (int kc = 0; kc < 4; ++kc) {
        xlo[kc] = *(const fvec4*)(xp + kc * 32 + quad * 8);
        xhi[kc] = *(const fvec4*)(xp + kc * 32 + quad * 8 + 4);
    }
    fvec4 ur[8];
#pragma unroll
    for (int ct = 0; ct < 8; ++ct)
        ur[ct] = *(const fvec4*)(drop_u + (size_t)rowc * D + ct * 16 + quad * 4);
    stage(0);

    // pack x to bf16 fragments
    bf16x8 xf[4];
#pragma unroll
    for (int kc = 0; kc < 4; ++kc) {
        uint4 xi;
        xi.x = pack_bf2(xlo[kc][0], xlo[kc][1]);
        xi.y = pack_bf2(xlo[kc][2], xlo[kc][3]);
        xi.z = pack_bf2(xhi[kc][0], xhi[kc][1]);
        xi.w = pack_bf2(xhi[kc][2], xhi[kc][3]);
        xf[kc] = __builtin_bit_cast(bf16x8, xi);
    }

    __syncthreads();   // staging + x + drop_u loads complete

    // compress dropout to 32-bit keep-mask (frees 32 VGPRs)
    unsigned dmask = 0;
#pragma unroll
    for (int ct = 0; ct < 8; ++ct)
#pragma unroll
        for (int c = 0; c < 4; ++c)
            dmask |= (ur[ct][c] < 0.8f) ? (1u << (ct * 4 + c)) : 0u;

#pragma unroll
    for (int pass = 0; pass < 3; ++pass) {
        f32x4 C[8];
#pragma unroll
        for (int ct = 0; ct < 8; ++ct) C[ct] = (f32x4){0.f, 0.f, 0.f, 0.f};

#pragma unroll
        for (int kc = 0; kc < 4; ++kc) {
#pragma unroll
            for (int ct = 0; ct < 8; ++ct) {
                // swizzled LDS read: row = ct*16+m16, unit = (kc*4+quad)^m16
                const unsigned short* wp =
                    ldsW + (size_t)(ct * 16 + m16) * 128 +
                    (((kc * 4 + quad) ^ m16) * 8);
                bf16x8 wf = *(const bf16x8*)wp;
                C[ct] = __builtin_amdgcn_mfma_f32_16x16x32_bf16(
                    wf, xf[kc], C[ct], 0, 0, 0);
            }
        }

        if (pass < 2) {
            __syncthreads();     // done reading ldsW for this pass
            stage(pass + 1);     // overlap next staging with epilogue
        }

        // epilogue (no loads left on the critical path)
        if (row < N) {
            if (pass == 2) {
#pragma unroll
                for (int ct = 0; ct < 8; ++ct) {
                    fvec4 r;
#pragma unroll
                    for (int c = 0; c < 4; ++c)
                        r[c] = C[ct][c] *
                               (((dmask >> (ct * 4 + c)) & 1u) ? 1.25f : 0.0f);
                    *(fvec4*)(out + (size_t)row * D + ct * 16 + quad * 4) = r;
                }
            } else {
                unsigned short* Yp = Y + (size_t)pass * N * D;
#pragma unroll
                for (int ct = 0; ct < 8; ++ct) {
                    uint2 pk;
                    pk.x = pack_bf2(C[ct][0], C[ct][1]);
                    pk.y = pack_bf2(C[ct][2], C[ct][3]);
                    *(uint2*)(Yp + (size_t)row * D + ct * 16 + quad * 4) = pk;
                }
            }
        }

        if (pass < 2) __syncthreads();   // next pass's W staged
    }
}

// ---------------------------------------------------------------------------
// K2: gather-sum + self-loop + ReLU.  One wave per output row.
// All four adj int4s (16 entries >= deg for ~90% of Poisson(12) rows) are
// issued up front as INDEPENDENT loads, then up to 4 guarded Y dwordx4 loads
// go out back-to-back -> 4-deep MLP, no dependent adj load in the common
// path. deg>16 falls back to a short loop. grp = lane>>4 picks the entry,
// l16 = lane&15 reads 16 B of that row. shfl_xor(16/32) cross-grp reduce;
// fully coalesced 8 B/lane RMW epilogue.
// ---------------------------------------------------------------------------
static __device__ __forceinline__ float bflo(unsigned u) {
    return __builtin_bit_cast(float, u << 16);
}
static __device__ __forceinline__ float bfhi(unsigned u) {
    return __builtin_bit_cast(float, u & 0xFFFF0000u);
}
static __device__ __forceinline__ int pick(int4 a, int grp) {
    return (grp == 0) ? a.x : (grp == 1) ? a.y : (grp == 2) ? a.z : a.w;
}
static __device__ __forceinline__ void acc8(float* acc, uint4 u) {
    acc[0] += bflo(u.x); acc[1] += bfhi(u.x);
    acc[2] += bflo(u.y); acc[3] += bfhi(u.y);
    acc[4] += bflo(u.z); acc[5] += bfhi(u.z);
    acc[6] += bflo(u.w); acc[7] += bfhi(u.w);
}

__global__ __launch_bounds__(256) void gather_kernel(
    const unsigned short* __restrict__ Y, const int* __restrict__ counts,
    const int* __restrict__ adj, float* __restrict__ out, int N)
{
    const int wave = threadIdx.x >> 6;
    const int v = blockIdx.x * 4 + wave;
    if (v >= N) return;
    const int lane = threadIdx.x & 63;
    const int grp = lane >> 4;
    const int l16 = lane & 15;

    int deg = counts[v];
    if (deg > CAP) deg = CAP;
    const int* ap = adj + (size_t)v * CAP;

    // 4 independent adj loads (cover entries 0..15)
    int4 a0 = *(const int4*)(ap);
    int4 a1 = *(const int4*)(ap + 4);
    int4 a2 = *(const int4*)(ap + 8);
    int4 a3 = *(const int4*)(ap + 12);

    // up to 4 guarded Y loads, all in flight together
    uint4 u0 = {0,0,0,0}, u1 = {0,0,0,0}, u2 = {0,0,0,0}, u3 = {0,0,0,0};
    if (grp      < deg) u0 = *(const uint4*)(Y + (size_t)pick(a0, grp) * D + l16 * 8);
    if (grp + 4  < deg) u1 = *(const uint4*)(Y + (size_t)pick(a1, grp) * D + l16 * 8);
    if (grp + 8  < deg) u2 = *(const uint4*)(Y + (size_t)pick(a2, grp) * D + l16 * 8);
    if (grp + 12 < deg) u3 = *(const uint4*)(Y + (size_t)pick(a3, grp) * D + l16 * 8);

    float acc[8];
#pragma unroll
    for (int i = 0; i < 8; ++i) acc[i] = 0.0f;
    acc8(acc, u0); acc8(acc, u1); acc8(acc, u2); acc8(acc, u3);

    // rare tail (deg > 16, ~10% of Poisson(12) rows)
    for (int j = 16; j < deg; j += 4) {
        if (j + grp < deg) {
            int4 a = *(const int4*)(ap + j);
            uint4 u = *(const uint4*)(Y + (size_t)pick(a, grp) * D + l16 * 8);
            acc8(acc, u);
        }
    }

#pragma unroll
    for (int i = 0; i < 8; ++i) {
        acc[i] += __shfl_xor(acc[i], 16, 64);
        acc[i] += __shfl_xor(acc[i], 32, 64);
    }

    float e0, e1;
    if (grp == 0)      { e0 = acc[0]; e1 = acc[1]; }
    else if (grp == 1) { e0 = acc[2]; e1 = acc[3]; }
    else if (grp == 2) { e0 = acc[4]; e1 = acc[5]; }
    else               { e0 = acc[6]; e1 = acc[7]; }

    float* po = out + (size_t)v * D + l16 * 8 + grp * 2;
    fvec2 o = *(fvec2*)po;
    o.x = fmaxf(o.x + e0, 0.0f);
    o.y = fmaxf(o.y + e1, 0.0f);
    *(fvec2*)po = o;
}

extern "C" void kernel_launch(void* const* d_in, const int* in_sizes, int n_in,
                              void* d_out, int out_size, void* d_ws, size_t ws_size,
                              hipStream_t stream)
{
    const float* x      = (const float*)d_in[0];
    const float* W_f    = (const float*)d_in[1];
    const float* W_b    = (const float*)d_in[2];
    const float* W_s    = (const float*)d_in[3];
    const float* drop_u = (const float*)d_in[4];
    const int*   send   = (const int*)d_in[5];
    const int*   recv   = (const int*)d_in[6];

    const int N = in_sizes[0] / D;   // 100000
    const int E = in_sizes[5];       // 600000

    float* out = (float*)d_out;

    // workspace layout (16B-aligned chunks):
    //   Wsw    : 3*128*128 bf16 (96 KB, pre-swizzled)
    //   Y      : 2*N*128 bf16 (51.2 MB)
    //   counts : N ints (0.4 MB)
    //   adj    : N*CAP ints (25.6 MB)
    unsigned short* Wsw = (unsigned short*)d_ws;
    unsigned short* Y   = Wsw + (size_t)3 * 128 * 128;
    int* counts = (int*)(Y + (size_t)2 * N * D);
    int* adj    = counts + ((N + 3) & ~3);

    const int Nb = (N + 63) / 64;                 // 1563 GEMM blocks
    const int fillBlocks = (2 * E + 255) / 256;   // 4688 fill blocks

    // P0: swizzled W prep + counts zeroing (one small dispatch)
    prep_zero<<<(3 * 128 * 128 + N + 255) / 256, 256, 0, stream>>>(
        W_f, W_b, W_s, Wsw, counts, N);

    // K1: fused MFMA GEMM + adjacency fill (tail placement — measured best)
    mm3_fill<<<Nb + fillBlocks, 256, 0, stream>>>(
        x, Wsw, drop_u, Y, out, send, recv, counts, adj, N, E, Nb);

    // K2: gather + self-loop + ReLU
    gather_kernel<<<(N + 3) / 4, 256, 0, stream>>>(Y, counts, adj, out, N);
}